// Round 1
// baseline (1310.200 us; speedup 1.0000x reference)
//
#include <hip/hip_runtime.h>
#include <hip/hip_bf16.h>

typedef unsigned short u16;
typedef __attribute__((ext_vector_type(8))) short bf16x8;
typedef __attribute__((ext_vector_type(4))) float f32x4;

#define FINF __builtin_huge_valf()

static __device__ __forceinline__ float bf2f(u16 v){ union{unsigned u; float f;} c; c.u = ((unsigned)v)<<16; return c.f; }
static __device__ __forceinline__ u16 f2bf(float f){ union{__hip_bfloat16 h; u16 u;} c; c.h = __float2bfloat16(f); return c.u; }

// ---------------------------------------------------------------- cvt
struct CvtArgs {
  const float* src[14];
  u16* dst[14];
  int n[14];
};
__global__ __launch_bounds__(256) void cvt_multi(CvtArgs a){
  int seg = blockIdx.y;
  const float* s = a.src[seg]; u16* d = a.dst[seg]; int n = a.n[seg];
  for (int i = (blockIdx.x*256 + threadIdx.x)*4; i < n; i += gridDim.x*256*4){
    float4 v = *(const float4*)(s + i);
    ushort4 o = { f2bf(v.x), f2bf(v.y), f2bf(v.z), f2bf(v.w) };
    *(ushort4*)(d + i) = o;
  }
}

// ---------------------------------------------------------------- GEMM  C = A @ B^T (+bias, epilogues)
// A[M,K] bf16, Bw[N,K] bf16 (weight layout (out,in) => NT gemm), K%64==0.
// EPI: 0=f32 out, 1=bf16 out, 2=f32 out + f32 residual(aux), 3=bf16 qgelu,
//      4=sim: relu-threshold * g_mask(aux,f32) -> bf16, 5=f32 out row-permuted (graph->y)
template<int EPI>
__global__ __launch_bounds__(256,2) void gemm_nt(
    const u16* __restrict__ A, const u16* __restrict__ Bw,
    const float* __restrict__ bias, const float* aux, void* out,
    int M, int Nn, int K, int ldc, long aBatch, long bBatch, long cBatch)
{
  __shared__ u16 a_lds[128][72];
  __shared__ u16 b_lds[128][72];
  const int z = blockIdx.z;
  const u16* Az = A + (long)z*aBatch;
  const u16* Bz = Bw + (long)z*bBatch;
  const int n0 = blockIdx.x*128, m0 = blockIdx.y*128;
  const int t = threadIdx.x, lane = t & 63, wave = t >> 6;
  const int wr = wave >> 1, wc = wave & 1;
  const int r = lane & 15, kq = lane >> 4;

  uint4 ra[4], rb[4];
  int rowA[4], rowB[4], cc_[4], rw_[4];
  #pragma unroll
  for (int i=0;i<4;i++){
    int c = i*256 + t; rw_[i] = c>>3; cc_[i] = (c&7)*8;
    int ga = m0 + rw_[i]; rowA[i] = ga < M ? ga : M-1;
    int gb = n0 + rw_[i]; rowB[i] = gb < Nn ? gb : Nn-1;
  }

  f32x4 acc[4][4] = {};

  const int nkt = K >> 6;
  {
    int k0 = 0;
    #pragma unroll
    for (int i=0;i<4;i++){
      ra[i] = *(const uint4*)(Az + (long)rowA[i]*K + k0 + cc_[i]);
      rb[i] = *(const uint4*)(Bz + (long)rowB[i]*K + k0 + cc_[i]);
    }
  }
  for (int kt=0; kt<nkt; kt++){
    #pragma unroll
    for (int i=0;i<4;i++){
      *(uint4*)&a_lds[rw_[i]][cc_[i]] = ra[i];
      *(uint4*)&b_lds[rw_[i]][cc_[i]] = rb[i];
    }
    __syncthreads();
    if (kt+1 < nkt){
      int k0 = (kt+1)*64;
      #pragma unroll
      for (int i=0;i<4;i++){
        ra[i] = *(const uint4*)(Az + (long)rowA[i]*K + k0 + cc_[i]);
        rb[i] = *(const uint4*)(Bz + (long)rowB[i]*K + k0 + cc_[i]);
      }
    }
    #pragma unroll
    for (int kk=0; kk<2; kk++){
      bf16x8 af[4], bfr[4];
      #pragma unroll
      for (int i=0;i<4;i++) af[i] = *(const bf16x8*)&a_lds[wr*64 + i*16 + r][kk*32 + kq*8];
      #pragma unroll
      for (int j=0;j<4;j++) bfr[j] = *(const bf16x8*)&b_lds[wc*64 + j*16 + r][kk*32 + kq*8];
      #pragma unroll
      for (int i=0;i<4;i++)
        #pragma unroll
        for (int j=0;j<4;j++)
          acc[i][j] = __builtin_amdgcn_mfma_f32_16x16x32_bf16(af[i], bfr[j], acc[i][j], 0,0,0);
    }
    __syncthreads();
  }

  // epilogue: C row = (lane>>4)*4+reg, col = lane&15  [m89-verified layout]
  #pragma unroll
  for (int i=0;i<4;i++){
    #pragma unroll
    for (int j=0;j<4;j++){
      int gcol = n0 + wc*64 + j*16 + r;
      if (gcol >= Nn) continue;
      float bv = bias ? bias[gcol] : 0.f;
      #pragma unroll
      for (int rr=0; rr<4; rr++){
        int grow = m0 + wr*64 + i*16 + kq*4 + rr;
        if (grow >= M) continue;
        float v = acc[i][j][rr] + bv;
        if constexpr (EPI==0){
          ((float*)out)[(long)z*cBatch + (long)grow*ldc + gcol] = v;
        } else if constexpr (EPI==1){
          ((u16*)out)[(long)z*cBatch + (long)grow*ldc + gcol] = f2bf(v);
        } else if constexpr (EPI==2){
          long idx = (long)z*cBatch + (long)grow*ldc + gcol;
          ((float*)out)[idx] = aux[idx] + v;
        } else if constexpr (EPI==3){
          float g = v / (1.f + __expf(-1.702f*v));
          ((u16*)out)[(long)z*cBatch + (long)grow*ldc + gcol] = f2bf(g);
        } else if constexpr (EPI==4){
          float adj = v < 0.f ? 0.f : v;          // where(sim < 0, 0, sim)
          float gmv = aux[(long)grow*Nn + gcol];  // g_mask (shared across batch)
          ((u16*)out)[(long)z*cBatch + (long)grow*ldc + gcol] = f2bf(adj*gmv);
        } else if constexpr (EPI==5){
          int b = grow/1568, n = grow%1568, tt = n/196, lp = n%196;
          int yrow = (1+lp)*32 + tt*4 + b;
          ((float*)out)[(long)yrow*ldc + gcol] = v;
        }
      }
    }
  }
}

// ---------------------------------------------------------------- flash attention
// per block: one (batch z, head h), 64 query rows (16/wave). 64-key tiles.
// MASKED: score = (q.k/8)*gm ; gm==0 -> -inf.  else plain q.k/8 with key>=nk dead.
template<bool MASKED>
__global__ __launch_bounds__(256,2) void flash_attn(
    const u16* __restrict__ QKV, const u16* __restrict__ gmask, u16* __restrict__ Out,
    int nq, int nk, long qBatch, long qRow, long oBatch, long oRow, long gmBatch)
{
  __shared__ u16 k_lds[64][72];
  __shared__ u16 v_lds[64][72];
  __shared__ u16 p_lds[4][16][72];
  const int h = blockIdx.y, z = blockIdx.z;
  const int t = threadIdx.x, lane = t&63, wave = t>>6;
  const int r = lane&15, kq = lane>>4;
  const u16* Qb = QKV + (long)z*qBatch + h*64;
  const u16* Kb = Qb + 512;
  const u16* Vb = Qb + 1024;
  const int q0 = blockIdx.x*64 + wave*16;

  bf16x8 qf0, qf1;
  {
    int qi = q0 + r; if (qi > nq-1) qi = nq-1;
    const u16* qp = Qb + (long)qi*qRow + kq*8;
    qf0 = *(const bf16x8*)qp;
    qf1 = *(const bf16x8*)(qp + 32);
  }

  float m_[4] = {-FINF,-FINF,-FINF,-FINF};
  float l_[4] = {0,0,0,0};
  f32x4 o_[4] = {};

  const int nkt = (nk + 63) >> 6;
  for (int kt=0; kt<nkt; kt++){
    #pragma unroll
    for (int i=0;i<2;i++){
      int c = i*256 + t; int row = c>>3, cc = (c&7)*8;
      int j = kt*64 + row; if (j > nk-1) j = nk-1;
      *(uint4*)&k_lds[row][cc] = *(const uint4*)(Kb + (long)j*qRow + cc);
      *(uint4*)&v_lds[row][cc] = *(const uint4*)(Vb + (long)j*qRow + cc);
    }
    __syncthreads();

    float s[4][4];
    #pragma unroll
    for (int sub=0; sub<4; sub++){
      bf16x8 kf0 = *(const bf16x8*)&k_lds[sub*16 + r][kq*8];
      bf16x8 kf1 = *(const bf16x8*)&k_lds[sub*16 + r][32 + kq*8];
      f32x4 sc = {};
      sc = __builtin_amdgcn_mfma_f32_16x16x32_bf16(qf0, kf0, sc, 0,0,0);
      sc = __builtin_amdgcn_mfma_f32_16x16x32_bf16(qf1, kf1, sc, 0,0,0);
      #pragma unroll
      for (int rr=0;rr<4;rr++) s[sub][rr] = sc[rr];
    }
    #pragma unroll
    for (int sub=0; sub<4; sub++){
      int key = kt*64 + sub*16 + r;
      bool kdead = key >= nk;
      #pragma unroll
      for (int rr=0;rr<4;rr++){
        float sv = s[sub][rr]*0.125f;
        if constexpr (MASKED){
          int qrow = q0 + kq*4 + rr; if (qrow > nq-1) qrow = nq-1;
          int kc = kdead ? nk-1 : key;
          u16 g = gmask[(long)z*gmBatch + (long)qrow*nk + kc];
          if (g == 0 || kdead) sv = -FINF; else sv *= bf2f(g);
        } else {
          if (kdead) sv = -FINF;
        }
        s[sub][rr] = sv;
      }
    }
    // online softmax update (rows live in 16-lane groups)
    #pragma unroll
    for (int rr=0;rr<4;rr++){
      float mx = fmaxf(fmaxf(s[0][rr],s[1][rr]), fmaxf(s[2][rr],s[3][rr]));
      #pragma unroll
      for (int d=1; d<16; d<<=1) mx = fmaxf(mx, __shfl_xor(mx, d));
      float mnew = fmaxf(m_[rr], mx);
      float fac = (m_[rr] == -FINF) ? 0.f : __expf(m_[rr] - mnew);
      float ps = 0.f;
      #pragma unroll
      for (int sub=0;sub<4;sub++){
        float p = (s[sub][rr] == -FINF) ? 0.f : __expf(s[sub][rr] - mnew);
        s[sub][rr] = p; ps += p;
      }
      #pragma unroll
      for (int d=1; d<16; d<<=1) ps += __shfl_xor(ps, d);
      l_[rr] = l_[rr]*fac + ps;
      m_[rr] = mnew;
      o_[0][rr]*=fac; o_[1][rr]*=fac; o_[2][rr]*=fac; o_[3][rr]*=fac;
    }
    // P -> lds (per-wave region), then PV
    #pragma unroll
    for (int rr=0;rr<4;rr++){
      #pragma unroll
      for (int sub=0;sub<4;sub++)
        p_lds[wave][kq*4+rr][sub*16+r] = f2bf(s[sub][rr]);
    }
    #pragma unroll
    for (int c=0;c<2;c++){
      bf16x8 pf = *(const bf16x8*)&p_lds[wave][r][c*32 + kq*8];
      #pragma unroll
      for (int j=0;j<4;j++){
        bf16x8 vf;
        #pragma unroll
        for (int i=0;i<8;i++)
          ((u16*)&vf)[i] = v_lds[c*32 + kq*8 + i][j*16 + r];
        o_[j] = __builtin_amdgcn_mfma_f32_16x16x32_bf16(pf, vf, o_[j], 0,0,0);
      }
    }
    __syncthreads();
  }

  #pragma unroll
  for (int rr=0;rr<4;rr++){
    int qrow = q0 + kq*4 + rr;
    if (qrow >= nq) continue;
    float inv = l_[rr] > 0.f ? 1.f/l_[rr] : 0.f;
    #pragma unroll
    for (int j=0;j<4;j++)
      Out[(long)z*oBatch + (long)qrow*oRow + h*64 + j*16 + r] = f2bf(o_[j][rr]*inv);
  }
}

// ---------------------------------------------------------------- LayerNorm rows of 512, f32 in -> bf16 out
__global__ __launch_bounds__(256) void ln_rows(const float* __restrict__ in,
    const float* __restrict__ g, const float* __restrict__ b, u16* __restrict__ out, int rows)
{
  int wave = threadIdx.x >> 6, lane = threadIdx.x & 63;
  int row = blockIdx.x*4 + wave;
  if (row >= rows) return;
  const float4* x = (const float4*)(in + (long)row*512);
  float4 v0 = x[lane], v1 = x[lane+64];
  float s  = v0.x+v0.y+v0.z+v0.w + v1.x+v1.y+v1.z+v1.w;
  float ss = v0.x*v0.x+v0.y*v0.y+v0.z*v0.z+v0.w*v0.w + v1.x*v1.x+v1.y*v1.y+v1.z*v1.z+v1.w*v1.w;
  #pragma unroll
  for (int d=1; d<64; d<<=1){ s += __shfl_xor(s,d); ss += __shfl_xor(ss,d); }
  float mean = s * (1.f/512.f);
  float var = ss * (1.f/512.f) - mean*mean;
  float rs = rsqrtf(var + 1e-5f);
  const float4* gg = (const float4*)g; const float4* bb = (const float4*)b;
  float4 g0 = gg[lane], g1 = gg[lane+64], b0 = bb[lane], b1 = bb[lane+64];
  u16* o = out + (long)row*512;
  ushort4 o0 = { f2bf((v0.x-mean)*rs*g0.x + b0.x), f2bf((v0.y-mean)*rs*g0.y + b0.y),
                 f2bf((v0.z-mean)*rs*g0.z + b0.z), f2bf((v0.w-mean)*rs*g0.w + b0.w) };
  ushort4 o1 = { f2bf((v1.x-mean)*rs*g1.x + b1.x), f2bf((v1.y-mean)*rs*g1.y + b1.y),
                 f2bf((v1.z-mean)*rs*g1.z + b1.z), f2bf((v1.w-mean)*rs*g1.w + b1.w) };
  *(ushort4*)(o + lane*4) = o0;
  *(ushort4*)(o + 256 + lane*4) = o1;
}

// ---------------------------------------------------------------- loc rows: write xn (L2-normalized) and plain bf16 copy
__global__ __launch_bounds__(256) void locprep(const float* __restrict__ y0,
    u16* __restrict__ xn, u16* __restrict__ locb)
{
  int wave = threadIdx.x >> 6, lane = threadIdx.x & 63;
  int rr = blockIdx.x*4 + wave;                 // 0..6271 = b*1568 + t*196 + lp
  int bb = rr/1568, n = rr%1568, tt = n/196, lp = n%196;
  const float4* x = (const float4*)(y0 + ((long)((bb*8+tt)*197) + 1 + lp)*512);
  float4 v0 = x[lane], v1 = x[lane+64];
  float ss = v0.x*v0.x+v0.y*v0.y+v0.z*v0.z+v0.w*v0.w + v1.x*v1.x+v1.y*v1.y+v1.z*v1.z+v1.w*v1.w;
  #pragma unroll
  for (int d=1; d<64; d<<=1) ss += __shfl_xor(ss,d);
  float sc = 1.f / fmaxf(sqrtf(ss), 1e-12f);
  u16* ox = xn + (long)rr*512;
  u16* ol = locb + (long)rr*512;
  ushort4 a0 = { f2bf(v0.x*sc), f2bf(v0.y*sc), f2bf(v0.z*sc), f2bf(v0.w*sc) };
  ushort4 a1 = { f2bf(v1.x*sc), f2bf(v1.y*sc), f2bf(v1.z*sc), f2bf(v1.w*sc) };
  ushort4 c0 = { f2bf(v0.x), f2bf(v0.y), f2bf(v0.z), f2bf(v0.w) };
  ushort4 c1 = { f2bf(v1.x), f2bf(v1.y), f2bf(v1.z), f2bf(v1.w) };
  *(ushort4*)(ox + lane*4) = a0;  *(ushort4*)(ox + 256 + lane*4) = a1;
  *(ushort4*)(ol + lane*4) = c0;  *(ushort4*)(ol + 256 + lane*4) = c1;
}

// ---------------------------------------------------------------- tiny message-path attention S=8,Bt=4,H=8
__global__ __launch_bounds__(64) void msg_attn(const u16* __restrict__ mqkv, u16* __restrict__ matt){
  __shared__ float q_s[8][64], k_s[8][64], v_s[8][64];
  int bh = blockIdx.x; int bt = bh>>3, h = bh&7;
  int lane = threadIdx.x;
  int row = lane>>3, cc = (lane&7)*8;
  #pragma unroll
  for (int e=0;e<8;e++){
    long base = (long)(row*4 + bt)*1536 + h*64 + cc + e;
    q_s[row][cc+e] = bf2f(mqkv[base]);
    k_s[row][cc+e] = bf2f(mqkv[base + 512]);
    v_s[row][cc+e] = bf2f(mqkv[base + 1024]);
  }
  __syncthreads();
  int q = lane>>3, k = lane&7;
  float s = 0.f;
  #pragma unroll 16
  for (int d=0; d<64; d++) s += q_s[q][d]*k_s[k][d];
  s *= 0.125f;
  float mx = s;
  #pragma unroll
  for (int d=1; d<8; d<<=1) mx = fmaxf(mx, __shfl_xor(mx,d));
  float p = __expf(s - mx), ps = p;
  #pragma unroll
  for (int d=1; d<8; d<<=1) ps += __shfl_xor(ps,d);
  p /= ps;
  for (int d=0; d<64; d++){
    float ov = p * v_s[k][d];
    #pragma unroll
    for (int m=1; m<8; m<<=1) ov += __shfl_xor(ov,m);
    if (k == (d>>3)) matt[(long)(q*4 + bt)*512 + h*64 + d] = f2bf(ov);
  }
}

// ---------------------------------------------------------------- small copies / permutes
__global__ __launch_bounds__(256) void gather_glob(const float* __restrict__ y0, float* __restrict__ glob){
  int idx = blockIdx.x*256 + threadIdx.x;      // 16384
  int orow = idx>>9, d = idx&511;
  int tt = orow>>2, bb = orow&3;
  glob[idx] = y0[((long)(bb*8+tt)*197)*512 + d];
}
__global__ __launch_bounds__(256) void copy32(const float* __restrict__ glob, float* __restrict__ y){
  int idx = blockIdx.x*256 + threadIdx.x;
  y[idx] = glob[idx];
}
__global__ __launch_bounds__(256) void permute_out(const float* __restrict__ y, float* __restrict__ out){
  int idx = blockIdx.x*256 + threadIdx.x;      // 807168 float4
  int d4 = idx & 127;
  int rest = idx >> 7;                          // (b*8+t)*197 + l
  int l = rest % 197;
  int bt = rest / 197;
  int tt = bt & 7, bb = bt >> 3;
  ((float4*)out)[idx] = ((const float4*)y)[(l*32 + tt*4 + bb)*128 + d4];
}

// ---------------------------------------------------------------- launch
extern "C" void kernel_launch(void* const* d_in, const int* in_sizes, int n_in,
                              void* d_out, int out_size, void* d_ws, size_t ws_size,
                              hipStream_t stream)
{
  const float* x      = (const float*)d_in[0];
  const float* proj_w = (const float*)d_in[1];
  const float* proj_b = (const float*)d_in[2];
  const float* m_ln1g = (const float*)d_in[3];
  const float* m_ln1b = (const float*)d_in[4];
  const float* m_inw  = (const float*)d_in[5];
  const float* m_inb  = (const float*)d_in[6];
  const float* m_outw = (const float*)d_in[7];
  const float* m_outb = (const float*)d_in[8];
  const float* m_ln2g = (const float*)d_in[9];
  const float* m_ln2b = (const float*)d_in[10];
  const float* m_fcw  = (const float*)d_in[11];
  const float* m_fcb  = (const float*)d_in[12];
  const float* m_pw   = (const float*)d_in[13];
  const float* m_pb   = (const float*)d_in[14];
  const float* g_wq = (const float*)d_in[15]; const float* g_bq = (const float*)d_in[16];
  const float* g_wk = (const float*)d_in[17]; const float* g_bk = (const float*)d_in[18];
  const float* g_wv = (const float*)d_in[19]; const float* g_bv = (const float*)d_in[20];
  const float* g_wo = (const float*)d_in[21]; const float* g_bo = (const float*)d_in[22];
  const float* ln1g = (const float*)d_in[23]; const float* ln1b = (const float*)d_in[24];
  const float* a_inw = (const float*)d_in[25]; const float* a_inb = (const float*)d_in[26];
  const float* a_outw = (const float*)d_in[27]; const float* a_outb = (const float*)d_in[28];
  const float* ln2g = (const float*)d_in[29]; const float* ln2b = (const float*)d_in[30];
  const float* fcw = (const float*)d_in[31]; const float* fcb = (const float*)d_in[32];
  const float* pw = (const float*)d_in[33]; const float* pb = (const float*)d_in[34];
  const float* g_mask = (const float*)d_in[35];

  if (ws_size < (size_t)99753984) return;   // layout below needs ~95.1 MiB

  char* ws = (char*)d_ws;
  u16* WB = (u16*)ws;
  const long WPROJ=0, WMIN=262144, WMOUT=1048576, WMFC=1310720, WMP=2359296,
             WGQ=3407872, WGK=3670016, WGV=3932160, WGO=4194304,
             WAIN=4456448, WAOUT=5242880, WFC=5505024, WP=6553600;
  float* y0   = (float*)(ws + 15204352);
  float* y    = (float*)(ws + 28114944);
  u16* lnbuf  = (u16*)(ws + 41025536);   // xn / ln outputs [6304][512]
  u16* locb   = (u16*)(ws + 47480832);   // [6272][512]
  u16* qkv    = (u16*)(ws + 53903360);   // [6304][1536]
  u16* xb     = (u16*)(ws + 73269248);   // aliases gm / hbuf (disjoint lifetimes)
  u16* gm     = (u16*)(ws + 73269248);   // [4][1568][1568] bf16
  u16* hbuf   = (u16*)(ws + 73269248);   // [6304][2048] bf16
  u16* obuf   = (u16*)(ws + 92938240);   // [6304][512] bf16
  float* glob = (float*)(ws + 99393536); // [32][512] f32
  u16* mlnb   = (u16*)(ws + 99459072);
  u16* mqkv   = (u16*)(ws + 99491840);
  u16* matt   = (u16*)(ws + 99590144);
  u16* mh     = (u16*)(ws + 99622912);

  // 1. all f32->bf16 conversions (weights + x)
  CvtArgs ca;
  auto setseg=[&](int i, const float* s, u16* d, int n){ ca.src[i]=s; ca.dst[i]=d; ca.n[i]=n; };
  setseg(0,  x,      xb,       6304*512);
  setseg(1,  proj_w, WB+WPROJ, 262144);
  setseg(2,  m_inw,  WB+WMIN,  786432);
  setseg(3,  m_outw, WB+WMOUT, 262144);
  setseg(4,  m_fcw,  WB+WMFC,  1048576);
  setseg(5,  m_pw,   WB+WMP,   1048576);
  setseg(6,  g_wq,   WB+WGQ,   262144);
  setseg(7,  g_wk,   WB+WGK,   262144);
  setseg(8,  g_wv,   WB+WGV,   262144);
  setseg(9,  g_wo,   WB+WGO,   262144);
  setseg(10, a_inw,  WB+WAIN,  786432);
  setseg(11, a_outw, WB+WAOUT, 262144);
  setseg(12, fcw,    WB+WFC,   1048576);
  setseg(13, pw,     WB+WP,    1048576);
  cvt_multi<<<dim3(128,14), 256, 0, stream>>>(ca);

  // 2. x @ proj_w^T + proj_b -> y0 (f32)
  gemm_nt<0><<<dim3(4,50), 256, 0, stream>>>(xb, WB+WPROJ, proj_b, nullptr, y0, 6304,512,512,512, 0,0,0);

  // 3. global tokens (l==0) -> glob[32][512], rows (t*4+b)
  gather_glob<<<64,256,0,stream>>>(y0, glob);

  // 4. message-passing resblock x2
  for (int it=0; it<2; ++it){
    ln_rows<<<8,256,0,stream>>>(glob, m_ln1g, m_ln1b, mlnb, 32);
    gemm_nt<1><<<dim3(12,1),256,0,stream>>>(mlnb, WB+WMIN, m_inb, nullptr, mqkv, 32,1536,512,1536, 0,0,0);
    msg_attn<<<32,64,0,stream>>>(mqkv, matt);
    gemm_nt<2><<<dim3(4,1),256,0,stream>>>(matt, WB+WMOUT, m_outb, glob, glob, 32,512,512,512, 0,0,0);
    ln_rows<<<8,256,0,stream>>>(glob, m_ln2g, m_ln2b, mlnb, 32);
    gemm_nt<3><<<dim3(16,1),256,0,stream>>>(mlnb, WB+WMFC, m_fcb, nullptr, mh, 32,2048,512,2048, 0,0,0);
    gemm_nt<2><<<dim3(4,1),256,0,stream>>>(mh, WB+WMP, m_pb, glob, glob, 32,512,2048,512, 0,0,0);
  }

  // 5. loc rows -> xn (normalized, ->lnbuf) + plain bf16 (->locb)
  locprep<<<1568,256,0,stream>>>(y0, lnbuf, locb);

  // 6. sim = xn@xn^T per batch; gm = relu-thresholded * g_mask (bf16)
  gemm_nt<4><<<dim3(13,13,4),256,0,stream>>>(lnbuf, lnbuf, nullptr, g_mask, gm,
      1568,1568,512,1568, 1568L*512, 1568L*512, 1568L*1568);

  // 7. graph Q,K,V projections into qkv[6272][1536]
  gemm_nt<1><<<dim3(4,49),256,0,stream>>>(locb, WB+WGQ, g_bq, nullptr, qkv+0,    6272,512,512,1536, 0,0,0);
  gemm_nt<1><<<dim3(4,49),256,0,stream>>>(locb, WB+WGK, g_bk, nullptr, qkv+512,  6272,512,512,1536, 0,0,0);
  gemm_nt<1><<<dim3(4,49),256,0,stream>>>(locb, WB+WGV, g_bv, nullptr, qkv+1024, 6272,512,512,1536, 0,0,0);

  // 8. masked graph attention -> obuf[6272][512]
  flash_attn<true><<<dim3(25,8,4),256,0,stream>>>(qkv, gm, obuf,
      1568,1568, 1568L*1536, 1536, 1568L*512, 512, 1568L*1568);

  // 9. out-proj with row permutation directly into y rows 32..6303
  gemm_nt<5><<<dim3(4,49),256,0,stream>>>(obuf, WB+WGO, g_bo, nullptr, y, 6272,512,512,512, 0,0,0);

  // 10. y rows 0..31 = glob
  copy32<<<64,256,0,stream>>>(glob, y);

  // 11-14. final MHA: y += attn(ln(y))
  ln_rows<<<1576,256,0,stream>>>(y, ln1g, ln1b, lnbuf, 6304);
  gemm_nt<1><<<dim3(12,50),256,0,stream>>>(lnbuf, WB+WAIN, a_inb, nullptr, qkv, 6304,1536,512,1536, 0,0,0);
  flash_attn<false><<<dim3(4,8,32),256,0,stream>>>(qkv, nullptr, obuf,
      197,197, 1536, 32L*1536, 512, 32L*512, 0);
  gemm_nt<2><<<dim3(4,50),256,0,stream>>>(obuf, WB+WAOUT, a_outb, y, y, 6304,512,512,512, 0,0,0);

  // 15-17. MLP: y += qgelu(ln2(y)@fcw^T+fcb)@pw^T+pb
  ln_rows<<<1576,256,0,stream>>>(y, ln2g, ln2b, lnbuf, 6304);
  gemm_nt<3><<<dim3(16,50),256,0,stream>>>(lnbuf, WB+WFC, fcb, nullptr, hbuf, 6304,2048,512,2048, 0,0,0);
  gemm_nt<2><<<dim3(4,50),256,0,stream>>>(hbuf, WB+WP, pb, y, y, 6304,512,2048,512, 0,0,0);

  // 18. out[b][t][l][d] = y[l*32 + t*4 + b][d]
  permute_out<<<3153,256,0,stream>>>(y, (float*)d_out);
}

// Round 2
// 629.681 us; speedup vs baseline: 2.0807x; 2.0807x over previous
//
#include <hip/hip_runtime.h>
#include <hip/hip_bf16.h>

typedef unsigned short u16;
typedef __attribute__((ext_vector_type(8))) short bf16x8;
typedef __attribute__((ext_vector_type(4))) float f32x4;

#define FINF __builtin_huge_valf()

static __device__ __forceinline__ float bf2f(u16 v){ union{unsigned u; float f;} c; c.u = ((unsigned)v)<<16; return c.f; }
static __device__ __forceinline__ u16 f2bf(float f){ union{__hip_bfloat16 h; u16 u;} c; c.h = __float2bfloat16(f); return c.u; }

// async global->LDS, 16B per lane; LDS dest = wave-uniform base + lane*16
static __device__ __forceinline__ void gload16(const void* g, void* l){
  __builtin_amdgcn_global_load_lds(
      (const __attribute__((address_space(1))) void*)g,
      (__attribute__((address_space(3))) void*)l, 16, 0, 0);
}

// ---------------------------------------------------------------- cvt
struct CvtArgs {
  const float* src[14];
  u16* dst[14];
  int n[14];
};
__global__ __launch_bounds__(256) void cvt_multi(CvtArgs a){
  int seg = blockIdx.y;
  const float* s = a.src[seg]; u16* d = a.dst[seg]; int n = a.n[seg];
  for (int i = (blockIdx.x*256 + threadIdx.x)*4; i < n; i += gridDim.x*256*4){
    float4 v = *(const float4*)(s + i);
    ushort4 o = { f2bf(v.x), f2bf(v.y), f2bf(v.z), f2bf(v.w) };
    *(ushort4*)(d + i) = o;
  }
}

__global__ __launch_bounds__(256) void concat_bias(const float* a, const float* b, const float* c, float* o){
  int i = blockIdx.x*256 + threadIdx.x;   // 1536
  o[i] = i < 512 ? a[i] : (i < 1024 ? b[i-512] : c[i-1024]);
}

// ---------------------------------------------------------------- GEMM  C = A @ B^T (+bias, epilogues)
// m97 structure: linear LDS tiles [128][64] u16, global_load_lds width16 staging
// with inverse-swizzled source; reads XOR-swizzle u16-index bits 3..5 by (row&7).
// EPI: 0=f32 out, 1=bf16 out, 2=f32 out + f32 residual(aux), 3=bf16 qgelu,
//      4=sim: relu-threshold * g_mask(aux,f32) -> bf16, 5=f32 out row-permuted
template<int EPI>
__global__ __launch_bounds__(256,2) void gemm_nt(
    const u16* __restrict__ A, const u16* __restrict__ Bw,
    const float* __restrict__ bias, const float* aux, void* out,
    int M, int Nn, int K, int ldc, long aBatch, long bBatch, long cBatch)
{
  __shared__ __align__(16) u16 a_lds[8192];
  __shared__ __align__(16) u16 b_lds[8192];
  const int z = blockIdx.z;
  const u16* Az = A + (long)z*aBatch;
  const u16* Bz = Bw + (long)z*bBatch;
  const int n0 = blockIdx.x*128, m0 = blockIdx.y*128;
  const int t = threadIdx.x, lane = t & 63, wave = t >> 6;
  const int wr = wave >> 1, wc = wave & 1;
  const int r = lane & 15, kq = lane >> 4;

  // staging geometry: round i covers rows i*32 + (t>>3), 16B per lane
  const int srow = t >> 3;
  const int scol = ((((t&7)*16) ^ ((srow&7)<<4)) >> 1);   // swizzled source col (u16)
  int rowA[4], rowB[4];
  #pragma unroll
  for (int i=0;i<4;i++){
    int rloc = i*32 + srow;
    int ga = m0 + rloc; rowA[i] = ga < M ? ga : M-1;
    int gb = n0 + rloc; rowB[i] = gb < Nn ? gb : Nn-1;
  }

  f32x4 acc[4][4] = {};
  const int nkt = K >> 6;
  for (int kt=0; kt<nkt; kt++){
    const long koff = (long)kt*64 + scol;
    #pragma unroll
    for (int i=0;i<4;i++)
      gload16(Az + (long)rowA[i]*K + koff, (char*)a_lds + i*4096 + wave*1024);
    #pragma unroll
    for (int i=0;i<4;i++)
      gload16(Bz + (long)rowB[i]*K + koff, (char*)b_lds + i*4096 + wave*1024);
    __syncthreads();
    #pragma unroll
    for (int kk=0; kk<2; kk++){
      bf16x8 af[4], bfr[4];
      #pragma unroll
      for (int i=0;i<4;i++){
        int rw = wr*64 + i*16 + r;
        af[i] = *(const bf16x8*)&a_lds[rw*64 + ((kk*32 + kq*8) ^ ((rw&7)<<3))];
      }
      #pragma unroll
      for (int j=0;j<4;j++){
        int rw = wc*64 + j*16 + r;
        bfr[j] = *(const bf16x8*)&b_lds[rw*64 + ((kk*32 + kq*8) ^ ((rw&7)<<3))];
      }
      #pragma unroll
      for (int i=0;i<4;i++)
        #pragma unroll
        for (int j=0;j<4;j++)
          acc[i][j] = __builtin_amdgcn_mfma_f32_16x16x32_bf16(af[i], bfr[j], acc[i][j], 0,0,0);
    }
    __syncthreads();
  }

  // epilogue: C row = (lane>>4)*4+reg, col = lane&15
  #pragma unroll
  for (int i=0;i<4;i++){
    #pragma unroll
    for (int j=0;j<4;j++){
      int gcol = n0 + wc*64 + j*16 + r;
      if (gcol >= Nn) continue;
      float bv = bias ? bias[gcol] : 0.f;
      #pragma unroll
      for (int rr=0; rr<4; rr++){
        int grow = m0 + wr*64 + i*16 + kq*4 + rr;
        if (grow >= M) continue;
        float v = acc[i][j][rr] + bv;
        if constexpr (EPI==0){
          ((float*)out)[(long)z*cBatch + (long)grow*ldc + gcol] = v;
        } else if constexpr (EPI==1){
          ((u16*)out)[(long)z*cBatch + (long)grow*ldc + gcol] = f2bf(v);
        } else if constexpr (EPI==2){
          long idx = (long)z*cBatch + (long)grow*ldc + gcol;
          ((float*)out)[idx] = aux[idx] + v;
        } else if constexpr (EPI==3){
          float g = v / (1.f + __expf(-1.702f*v));
          ((u16*)out)[(long)z*cBatch + (long)grow*ldc + gcol] = f2bf(g);
        } else if constexpr (EPI==4){
          float adj = v < 0.f ? 0.f : v;          // where(sim < 0, 0, sim)
          float gmv = aux[(long)grow*Nn + gcol];  // g_mask (shared across batch)
          ((u16*)out)[(long)z*cBatch + (long)grow*ldc + gcol] = f2bf(adj*gmv);
        } else if constexpr (EPI==5){
          int b = grow/1568, n = grow%1568, tt = n/196, lp = n%196;
          int yrow = (1+lp)*32 + tt*4 + b;
          ((float*)out)[(long)yrow*ldc + gcol] = v;
        }
      }
    }
  }
}

// ---------------------------------------------------------------- flash attention
// per block: one (batch z, head h), 64 query rows (16/wave). 64-key tiles.
// K and g_mask tiles staged via gload_lds (swizzled); V staged to regs and
// written transposed (V^T) to LDS so PV reads are vector ds_read_b128.
template<bool MASKED>
__global__ __launch_bounds__(256,2) void flash_attn(
    const u16* __restrict__ QKV, const u16* __restrict__ gmask, u16* __restrict__ Out,
    int nq, int nk, long qBatch, long qRow, long oBatch, long oRow, long gmBatch)
{
  __shared__ __align__(16) u16 k_lds[4096];
  __shared__ __align__(16) u16 g_lds[4096];
  __shared__ __align__(16) u16 vt[64*74];
  __shared__ u16 p_lds[4][16][72];
  const int h = blockIdx.y, z = blockIdx.z;
  const int t = threadIdx.x, lane = t&63, wave = t>>6;
  const int r = lane&15, kq = lane>>4;
  const u16* Qb = QKV + (long)z*qBatch + h*64;
  const u16* Kb = Qb + 512;
  const u16* Vb = Qb + 1024;
  const u16* Gz = gmask + (long)z*gmBatch;
  const int qt0 = blockIdx.x*64;
  const int q0 = qt0 + wave*16;

  bf16x8 qf0, qf1;
  {
    int qi = q0 + r; if (qi > nq-1) qi = nq-1;
    const u16* qp = Qb + (long)qi*qRow + kq*8;
    qf0 = *(const bf16x8*)qp;
    qf1 = *(const bf16x8*)(qp + 32);
  }

  const int srow = t>>3;                                  // 0..31
  const int scol = ((((t&7)*16) ^ ((srow&7)<<4)) >> 1);   // swizzled source col (u16)

  float m_[4] = {-FINF,-FINF,-FINF,-FINF};
  float l_[4] = {0,0,0,0};
  f32x4 o_[4] = {};

  const int nkt = (nk + 63) >> 6;
  for (int kt=0; kt<nkt; kt++){
    // ---- stage K (gload, swizzled)
    #pragma unroll
    for (int i=0;i<2;i++){
      int krow = i*32 + srow;
      int j = kt*64 + krow; if (j > nk-1) j = nk-1;
      gload16(Kb + (long)j*qRow + scol, (char*)k_lds + i*4096 + wave*1024);
    }
    // ---- stage g_mask tile (gload, swizzled); cols past nk read garbage, masked by kdead
    if constexpr (MASKED){
      #pragma unroll
      for (int i=0;i<2;i++){
        int grow = i*32 + srow;
        int qr = qt0 + grow; if (qr > nq-1) qr = nq-1;
        gload16(Gz + (long)qr*nk + kt*64 + scol, (char*)g_lds + i*4096 + wave*1024);
      }
    }
    // ---- stage V transposed: regs -> vt[d][key], stride 74
    #pragma unroll
    for (int i=0;i<2;i++){
      int c = i*256 + t; int vrow = c>>3, cc = (c&7)*8;
      int vj = kt*64 + vrow; if (vj > nk-1) vj = nk-1;
      uint4 vv = *(const uint4*)(Vb + (long)vj*qRow + cc);
      #pragma unroll
      for (int e=0;e<8;e++) vt[(cc+e)*74 + vrow] = ((const u16*)&vv)[e];
    }
    __syncthreads();

    // ---- QK^T
    float s[4][4];
    #pragma unroll
    for (int sub=0; sub<4; sub++){
      int rw = sub*16 + r; int sw = (rw&7)<<3;
      bf16x8 kf0 = *(const bf16x8*)&k_lds[rw*64 + ((kq*8) ^ sw)];
      bf16x8 kf1 = *(const bf16x8*)&k_lds[rw*64 + ((32 + kq*8) ^ sw)];
      f32x4 sc = {};
      sc = __builtin_amdgcn_mfma_f32_16x16x32_bf16(qf0, kf0, sc, 0,0,0);
      sc = __builtin_amdgcn_mfma_f32_16x16x32_bf16(qf1, kf1, sc, 0,0,0);
      #pragma unroll
      for (int rr=0;rr<4;rr++) s[sub][rr] = sc[rr];
    }
    // ---- mask
    #pragma unroll
    for (int sub=0; sub<4; sub++){
      int key = kt*64 + sub*16 + r;
      bool kdead = key >= nk;
      #pragma unroll
      for (int rr=0;rr<4;rr++){
        float sv = s[sub][rr]*0.125f;
        if constexpr (MASKED){
          int lrow = wave*16 + kq*4 + rr;   // q-local row within the 64-tile
          u16 g = g_lds[lrow*64 + ((sub*16+r) ^ ((lrow&7)<<3))];
          if (g == 0 || kdead) sv = -FINF; else sv *= bf2f(g);
        } else {
          if (kdead) sv = -FINF;
        }
        s[sub][rr] = sv;
      }
    }
    // ---- online softmax (rows live in 16-lane groups)
    #pragma unroll
    for (int rr=0;rr<4;rr++){
      float mx = fmaxf(fmaxf(s[0][rr],s[1][rr]), fmaxf(s[2][rr],s[3][rr]));
      #pragma unroll
      for (int d=1; d<16; d<<=1) mx = fmaxf(mx, __shfl_xor(mx, d));
      float mnew = fmaxf(m_[rr], mx);
      float fac = (m_[rr] == -FINF) ? 0.f : __expf(m_[rr] - mnew);
      float ps = 0.f;
      #pragma unroll
      for (int sub=0;sub<4;sub++){
        float p = (s[sub][rr] == -FINF) ? 0.f : __expf(s[sub][rr] - mnew);
        s[sub][rr] = p; ps += p;
      }
      #pragma unroll
      for (int d=1; d<16; d<<=1) ps += __shfl_xor(ps, d);
      l_[rr] = l_[rr]*fac + ps;
      m_[rr] = mnew;
      o_[0][rr]*=fac; o_[1][rr]*=fac; o_[2][rr]*=fac; o_[3][rr]*=fac;
    }
    // ---- P -> lds (per-wave region), then PV from V^T
    #pragma unroll
    for (int rr=0;rr<4;rr++){
      #pragma unroll
      for (int sub=0;sub<4;sub++)
        p_lds[wave][kq*4+rr][sub*16+r] = f2bf(s[sub][rr]);
    }
    #pragma unroll
    for (int c=0;c<2;c++){
      bf16x8 pf = *(const bf16x8*)&p_lds[wave][r][c*32 + kq*8];
      #pragma unroll
      for (int j=0;j<4;j++){
        bf16x8 vf = *(const bf16x8*)&vt[(j*16+r)*74 + c*32 + kq*8];
        o_[j] = __builtin_amdgcn_mfma_f32_16x16x32_bf16(pf, vf, o_[j], 0,0,0);
      }
    }
    __syncthreads();
  }

  #pragma unroll
  for (int rr=0;rr<4;rr++){
    int qrow = q0 + kq*4 + rr;
    if (qrow >= nq) continue;
    float inv = l_[rr] > 0.f ? 1.f/l_[rr] : 0.f;
    #pragma unroll
    for (int j=0;j<4;j++)
      Out[(long)z*oBatch + (long)qrow*oRow + h*64 + j*16 + r] = f2bf(o_[j][rr]*inv);
  }
}

// ---------------------------------------------------------------- LayerNorm rows of 512, f32 in -> bf16 out
__global__ __launch_bounds__(256) void ln_rows(const float* __restrict__ in,
    const float* __restrict__ g, const float* __restrict__ b, u16* __restrict__ out, int rows)
{
  int wave = threadIdx.x >> 6, lane = threadIdx.x & 63;
  int row = blockIdx.x*4 + wave;
  if (row >= rows) return;
  const float4* x = (const float4*)(in + (long)row*512);
  float4 v0 = x[lane], v1 = x[lane+64];
  float s  = v0.x+v0.y+v0.z+v0.w + v1.x+v1.y+v1.z+v1.w;
  float ss = v0.x*v0.x+v0.y*v0.y+v0.z*v0.z+v0.w*v0.w + v1.x*v1.x+v1.y*v1.y+v1.z*v1.z+v1.w*v1.w;
  #pragma unroll
  for (int d=1; d<64; d<<=1){ s += __shfl_xor(s,d); ss += __shfl_xor(ss,d); }
  float mean = s * (1.f/512.f);
  float var = ss * (1.f/512.f) - mean*mean;
  float rs = rsqrtf(var + 1e-5f);
  const float4* gg = (const float4*)g; const float4* bb = (const float4*)b;
  float4 g0 = gg[lane], g1 = gg[lane+64], b0 = bb[lane], b1 = bb[lane+64];
  u16* o = out + (long)row*512;
  ushort4 o0 = { f2bf((v0.x-mean)*rs*g0.x + b0.x), f2bf((v0.y-mean)*rs*g0.y + b0.y),
                 f2bf((v0.z-mean)*rs*g0.z + b0.z), f2bf((v0.w-mean)*rs*g0.w + b0.w) };
  ushort4 o1 = { f2bf((v1.x-mean)*rs*g1.x + b1.x), f2bf((v1.y-mean)*rs*g1.y + b1.y),
                 f2bf((v1.z-mean)*rs*g1.z + b1.z), f2bf((v1.w-mean)*rs*g1.w + b1.w) };
  *(ushort4*)(o + lane*4) = o0;
  *(ushort4*)(o + 256 + lane*4) = o1;
}

// ---------------------------------------------------------------- loc rows: write xn (L2-normalized) and plain bf16 copy
__global__ __launch_bounds__(256) void locprep(const float* __restrict__ y0,
    u16* __restrict__ xn, u16* __restrict__ locb)
{
  int wave = threadIdx.x >> 6, lane = threadIdx.x & 63;
  int rr = blockIdx.x*4 + wave;                 // 0..6271 = b*1568 + t*196 + lp
  int bb = rr/1568, n = rr%1568, tt = n/196, lp = n%196;
  const float4* x = (const float4*)(y0 + ((long)((bb*8+tt)*197) + 1 + lp)*512);
  float4 v0 = x[lane], v1 = x[lane+64];
  float ss = v0.x*v0.x+v0.y*v0.y+v0.z*v0.z+v0.w*v0.w + v1.x*v1.x+v1.y*v1.y+v1.z*v1.z+v1.w*v1.w;
  #pragma unroll
  for (int d=1; d<64; d<<=1) ss += __shfl_xor(ss,d);
  float sc = 1.f / fmaxf(sqrtf(ss), 1e-12f);
  u16* ox = xn + (long)rr*512;
  u16* ol = locb + (long)rr*512;
  ushort4 a0 = { f2bf(v0.x*sc), f2bf(v0.y*sc), f2bf(v0.z*sc), f2bf(v0.w*sc) };
  ushort4 a1 = { f2bf(v1.x*sc), f2bf(v1.y*sc), f2bf(v1.z*sc), f2bf(v1.w*sc) };
  ushort4 c0 = { f2bf(v0.x), f2bf(v0.y), f2bf(v0.z), f2bf(v0.w) };
  ushort4 c1 = { f2bf(v1.x), f2bf(v1.y), f2bf(v1.z), f2bf(v1.w) };
  *(ushort4*)(ox + lane*4) = a0;  *(ushort4*)(ox + 256 + lane*4) = a1;
  *(ushort4*)(ol + lane*4) = c0;  *(ushort4*)(ol + 256 + lane*4) = c1;
}

// ---------------------------------------------------------------- tiny message-path attention S=8,Bt=4,H=8
__global__ __launch_bounds__(64) void msg_attn(const u16* __restrict__ mqkv, u16* __restrict__ matt){
  __shared__ float q_s[8][64], k_s[8][64], v_s[8][64];
  int bh = blockIdx.x; int bt = bh>>3, h = bh&7;
  int lane = threadIdx.x;
  int row = lane>>3, cc = (lane&7)*8;
  #pragma unroll
  for (int e=0;e<8;e++){
    long base = (long)(row*4 + bt)*1536 + h*64 + cc + e;
    q_s[row][cc+e] = bf2f(mqkv[base]);
    k_s[row][cc+e] = bf2f(mqkv[base + 512]);
    v_s[row][cc+e] = bf2f(mqkv[base + 1024]);
  }
  __syncthreads();
  int q = lane>>3, k = lane&7;
  float s = 0.f;
  #pragma unroll 16
  for (int d=0; d<64; d++) s += q_s[q][d]*k_s[k][d];
  s *= 0.125f;
  float mx = s;
  #pragma unroll
  for (int d=1; d<8; d<<=1) mx = fmaxf(mx, __shfl_xor(mx,d));
  float p = __expf(s - mx), ps = p;
  #pragma unroll
  for (int d=1; d<8; d<<=1) ps += __shfl_xor(ps,d);
  p /= ps;
  for (int d=0; d<64; d++){
    float ov = p * v_s[k][d];
    #pragma unroll
    for (int m=1; m<8; m<<=1) ov += __shfl_xor(ov,m);
    if (k == (d>>3)) matt[(long)(q*4 + bt)*512 + h*64 + d] = f2bf(ov);
  }
}

// ---------------------------------------------------------------- small copies / permutes
__global__ __launch_bounds__(256) void gather_glob(const float* __restrict__ y0, float* __restrict__ glob){
  int idx = blockIdx.x*256 + threadIdx.x;      // 16384
  int orow = idx>>9, d = idx&511;
  int tt = orow>>2, bb = orow&3;
  glob[idx] = y0[((long)(bb*8+tt)*197)*512 + d];
}
__global__ __launch_bounds__(256) void copy32(const float* __restrict__ glob, float* __restrict__ y){
  int idx = blockIdx.x*256 + threadIdx.x;
  y[idx] = glob[idx];
}
__global__ __launch_bounds__(256) void permute_out(const float* __restrict__ y, float* __restrict__ out){
  int idx = blockIdx.x*256 + threadIdx.x;      // 807168 float4
  int d4 = idx & 127;
  int rest = idx >> 7;                          // (b*8+t)*197 + l
  int l = rest % 197;
  int bt = rest / 197;
  int tt = bt & 7, bb = bt >> 3;
  ((float4*)out)[idx] = ((const float4*)y)[(l*32 + tt*4 + bb)*128 + d4];
}

// ---------------------------------------------------------------- launch
extern "C" void kernel_launch(void* const* d_in, const int* in_sizes, int n_in,
                              void* d_out, int out_size, void* d_ws, size_t ws_size,
                              hipStream_t stream)
{
  const float* x      = (const float*)d_in[0];
  const float* proj_w = (const float*)d_in[1];
  const float* proj_b = (const float*)d_in[2];
  const float* m_ln1g = (const float*)d_in[3];
  const float* m_ln1b = (const float*)d_in[4];
  const float* m_inw  = (const float*)d_in[5];
  const float* m_inb  = (const float*)d_in[6];
  const float* m_outw = (const float*)d_in[7];
  const float* m_outb = (const float*)d_in[8];
  const float* m_ln2g = (const float*)d_in[9];
  const float* m_ln2b = (const float*)d_in[10];
  const float* m_fcw  = (const float*)d_in[11];
  const float* m_fcb  = (const float*)d_in[12];
  const float* m_pw   = (const float*)d_in[13];
  const float* m_pb   = (const float*)d_in[14];
  const float* g_wq = (const float*)d_in[15]; const float* g_bq = (const float*)d_in[16];
  const float* g_wk = (const float*)d_in[17]; const float* g_bk = (const float*)d_in[18];
  const float* g_wv = (const float*)d_in[19]; const float* g_bv = (const float*)d_in[20];
  const float* g_wo = (const float*)d_in[21]; const float* g_bo = (const float*)d_in[22];
  const float* ln1g = (const float*)d_in[23]; const float* ln1b = (const float*)d_in[24];
  const float* a_inw = (const float*)d_in[25]; const float* a_inb = (const float*)d_in[26];
  const float* a_outw = (const float*)d_in[27]; const float* a_outb = (const float*)d_in[28];
  const float* ln2g = (const float*)d_in[29]; const float* ln2b = (const float*)d_in[30];
  const float* fcw = (const float*)d_in[31]; const float* fcb = (const float*)d_in[32];
  const float* pw = (const float*)d_in[33]; const float* pb = (const float*)d_in[34];
  const float* g_mask = (const float*)d_in[35];

  if (ws_size < (size_t)99753984) return;

  char* ws = (char*)d_ws;
  u16* WB = (u16*)ws;
  const long WPROJ=0, WMIN=262144, WMOUT=1048576, WMFC=1310720, WMP=2359296,
             WGQ=3407872, WGK=3670016, WGV=3932160, WGO=4194304,
             WAIN=4456448, WAOUT=5242880, WFC=5505024, WP=6553600;
  float* y0   = (float*)(ws + 15204352);
  float* y    = (float*)(ws + 28114944);
  u16* lnbuf  = (u16*)(ws + 41025536);   // xn / ln outputs [6304][512]
  u16* locb   = (u16*)(ws + 47480832);   // [6272][512]
  u16* qkv    = (u16*)(ws + 53903360);   // [6304][1536]
  u16* xb     = (u16*)(ws + 73269248);   // aliases gm / hbuf (disjoint lifetimes)
  u16* gm     = (u16*)(ws + 73269248);   // [4][1568][1568] bf16
  u16* hbuf   = (u16*)(ws + 73269248);   // [6304][2048] bf16 (overruns into obuf; obuf dead then)
  u16* obuf   = (u16*)(ws + 92938240);   // [6304][512] bf16
  float* glob = (float*)(ws + 99393536); // [32][512] f32
  u16* mlnb   = (u16*)(ws + 99459072);
  u16* mqkv   = (u16*)(ws + 99491840);
  u16* matt   = (u16*)(ws + 99590144);
  u16* mh     = (u16*)(ws + 99622912);
  float* gbias = (float*)(ws + 99622912); // aliases mh (dead after message blocks)

  // 1. all f32->bf16 conversions (weights + x)
  CvtArgs ca;
  auto setseg=[&](int i, const float* s, u16* d, int n){ ca.src[i]=s; ca.dst[i]=d; ca.n[i]=n; };
  setseg(0,  x,      xb,       6304*512);
  setseg(1,  proj_w, WB+WPROJ, 262144);
  setseg(2,  m_inw,  WB+WMIN,  786432);
  setseg(3,  m_outw, WB+WMOUT, 262144);
  setseg(4,  m_fcw,  WB+WMFC,  1048576);
  setseg(5,  m_pw,   WB+WMP,   1048576);
  setseg(6,  g_wq,   WB+WGQ,   262144);
  setseg(7,  g_wk,   WB+WGK,   262144);
  setseg(8,  g_wv,   WB+WGV,   262144);
  setseg(9,  g_wo,   WB+WGO,   262144);
  setseg(10, a_inw,  WB+WAIN,  786432);
  setseg(11, a_outw, WB+WAOUT, 262144);
  setseg(12, fcw,    WB+WFC,   1048576);
  setseg(13, pw,     WB+WP,    1048576);
  cvt_multi<<<dim3(128,14), 256, 0, stream>>>(ca);

  // 2. x @ proj_w^T + proj_b -> y0 (f32)
  gemm_nt<0><<<dim3(4,50), 256, 0, stream>>>(xb, WB+WPROJ, proj_b, nullptr, y0, 6304,512,512,512, 0,0,0);

  // 3. global tokens (l==0) -> glob[32][512], rows (t*4+b)
  gather_glob<<<64,256,0,stream>>>(y0, glob);

  // 4. message-passing resblock x2
  for (int it=0; it<2; ++it){
    ln_rows<<<8,256,0,stream>>>(glob, m_ln1g, m_ln1b, mlnb, 32);
    gemm_nt<1><<<dim3(12,1),256,0,stream>>>(mlnb, WB+WMIN, m_inb, nullptr, mqkv, 32,1536,512,1536, 0,0,0);
    msg_attn<<<32,64,0,stream>>>(mqkv, matt);
    gemm_nt<2><<<dim3(4,1),256,0,stream>>>(matt, WB+WMOUT, m_outb, glob, glob, 32,512,512,512, 0,0,0);
    ln_rows<<<8,256,0,stream>>>(glob, m_ln2g, m_ln2b, mlnb, 32);
    gemm_nt<3><<<dim3(16,1),256,0,stream>>>(mlnb, WB+WMFC, m_fcb, nullptr, mh, 32,2048,512,2048, 0,0,0);
    gemm_nt<2><<<dim3(4,1),256,0,stream>>>(mh, WB+WMP, m_pb, glob, glob, 32,512,2048,512, 0,0,0);
  }

  // 4b. concat graph-attention biases into gbias[1536] (mh region now dead)
  concat_bias<<<6,256,0,stream>>>(g_bq, g_bk, g_bv, gbias);

  // 5. loc rows -> xn (normalized, ->lnbuf) + plain bf16 (->locb)
  locprep<<<1568,256,0,stream>>>(y0, lnbuf, locb);

  // 6. sim = xn@xn^T per batch; gm = relu-thresholded * g_mask (bf16)
  gemm_nt<4><<<dim3(13,13,4),256,0,stream>>>(lnbuf, lnbuf, nullptr, g_mask, gm,
      1568,1568,512,1568, 1568L*512, 1568L*512, 1568L*1568);

  // 7. graph Q,K,V fused projection (wq|wk|wv contiguous in WB) -> qkv[6272][1536]
  gemm_nt<1><<<dim3(12,49),256,0,stream>>>(locb, WB+WGQ, gbias, nullptr, qkv, 6272,1536,512,1536, 0,0,0);

  // 8. masked graph attention -> obuf[6272][512]
  flash_attn<true><<<dim3(25,8,4),256,0,stream>>>(qkv, gm, obuf,
      1568,1568, 1568L*1536, 1536, 1568L*512, 512, 1568L*1568);

  // 9. out-proj with row permutation directly into y rows 32..6303
  gemm_nt<5><<<dim3(4,49),256,0,stream>>>(obuf, WB+WGO, g_bo, nullptr, y, 6272,512,512,512, 0,0,0);

  // 10. y rows 0..31 = glob
  copy32<<<64,256,0,stream>>>(glob, y);

  // 11-14. final MHA: y += attn(ln(y))
  ln_rows<<<1576,256,0,stream>>>(y, ln1g, ln1b, lnbuf, 6304);
  gemm_nt<1><<<dim3(12,50),256,0,stream>>>(lnbuf, WB+WAIN, a_inb, nullptr, qkv, 6304,1536,512,1536, 0,0,0);
  flash_attn<false><<<dim3(4,8,32),256,0,stream>>>(qkv, nullptr, obuf,
      197,197, 1536, 32L*1536, 512, 32L*512, 0);
  gemm_nt<2><<<dim3(4,50),256,0,stream>>>(obuf, WB+WAOUT, a_outb, y, y, 6304,512,512,512, 0,0,0);

  // 15-17. MLP: y += qgelu(ln2(y)@fcw^T+fcb)@pw^T+pb
  ln_rows<<<1576,256,0,stream>>>(y, ln2g, ln2b, lnbuf, 6304);
  gemm_nt<3><<<dim3(16,50),256,0,stream>>>(lnbuf, WB+WFC, fcb, nullptr, hbuf, 6304,2048,512,2048, 0,0,0);
  gemm_nt<2><<<dim3(4,50),256,0,stream>>>(hbuf, WB+WP, pb, y, y, 6304,512,2048,512, 0,0,0);

  // 18. out[b][t][l][d] = y[l*32 + t*4 + b][d]
  permute_out<<<3153,256,0,stream>>>(y, (float*)d_out);
}